// Round 1
// baseline (342.244 us; speedup 1.0000x reference)
//
#include <hip/hip_runtime.h>

#define NB 32
#define NH 720
#define NW 1280
#define NHW (NH * NW)        // 921600
#define KTOP 1024
#define CAP 2048             // gather capacity per image (~830 expected)

// ---------------- K0: zero per-image candidate counters ----------------
__global__ void k_zero_counts(int* __restrict__ counts) {
  const int t = blockIdx.x * blockDim.x + threadIdx.x;
  if (t < NB) counts[t] = 0;
}

// ------- K1: zero the output map + gather candidates >= threshold -------
__global__ void k_zero_gather(const float* __restrict__ prob,
                              const float* __restrict__ thr_p,
                              float* __restrict__ out,
                              int* __restrict__ counts,
                              int* __restrict__ cand) {
  const float thr = thr_p[0];
  const int total4 = (NB * NHW) / 4;
  const int stride = gridDim.x * blockDim.x;
  const float4 z = make_float4(0.f, 0.f, 0.f, 0.f);
  for (int v = blockIdx.x * blockDim.x + threadIdx.x; v < total4; v += stride) {
    const float4 p = reinterpret_cast<const float4*>(prob)[v];
    reinterpret_cast<float4*>(out)[v] = z;
    const float vals[4] = {p.x, p.y, p.z, p.w};
#pragma unroll
    for (int c = 0; c < 4; ++c) {
      if (vals[c] >= thr) {
        const int e = v * 4 + c;
        const int img = e / NHW;
        const int within = e - img * NHW;
        const int pos = atomicAdd(&counts[img], 1);
        if (pos < CAP) cand[img * CAP + pos] = within;
      }
    }
  }
}

// plain zeroing (fallback path)
__global__ void k_zero_out(float* __restrict__ out) {
  const int total4 = (NB * NHW) / 4;
  const int stride = gridDim.x * blockDim.x;
  const float4 z = make_float4(0.f, 0.f, 0.f, 0.f);
  for (int v = blockIdx.x * blockDim.x + threadIdx.x; v < total4; v += stride)
    reinterpret_cast<float4*>(out)[v] = z;
}

// ---- K2: fused rank (stable sort order) + conflict flag, per candidate ----
// grid = (NB, CAP/256), block = 256. Each block stages the image's whole
// candidate list in LDS; thread j does one O(n) pass computing:
//   rank  = #{i : (s_i > s_j) or (s_i == s_j and idx_i < idx_j)}   (== top_k order)
//   conf  = exists i != j with iou(i,j) > 0.1
// Writes sorted (score, idx|conf<<31) to ws at position rank (rank < KTOP).
__global__ __launch_bounds__(256)
void k_rank_conflict(const float* __restrict__ prob,
                     const int* __restrict__ size_p,
                     const int* __restrict__ counts,
                     const int* __restrict__ cand,
                     float2* __restrict__ srt) {
  const int img = blockIdx.x;
  const int n = min(counts[img], CAP);
  const int j0 = blockIdx.y * 256;
  if (j0 >= n) return;
  const float S = (float)size_p[0];   // box side == 2*half (exact, even for odd size)
  const float A = 2.f * S * S;        // 2*area; iou>0.1  <=>  11*inter > A (exact ints)
  const float* ip = prob + (size_t)img * NHW;

  __shared__ float4 cd[CAP];          // (score, y, x, idx-bits)
  for (int i = threadIdx.x; i < n; i += 256) {
    const int e = cand[img * CAP + i];
    const int y = e / NW;
    const int x = e - y * NW;
    cd[i] = make_float4(ip[e], (float)y, (float)x, __int_as_float(e));
  }
  __syncthreads();

  const int j = j0 + threadIdx.x;
  if (j >= n) return;
  const float4 me = cd[j];
  const float sj = me.x, yj = me.y, xj = me.z;
  const int gj = __float_as_int(me.w);
  int r = 0;
  int conf = 0;
  for (int i = 0; i < n; ++i) {
    const float4 o = cd[i];                       // broadcast b128, conflict-free
    const int g2 = __float_as_int(o.w);
    r += (o.x > sj) || (o.x == sj && g2 < gj);    // stable top_k tie order
    const float iy = S - fabsf(yj - o.y);
    const float ix = S - fabsf(xj - o.z);
    const float inter = (fminf(iy, ix) > 0.f) ? iy * ix : 0.f;
    conf |= (int)((i != j) & (11.f * inter > A));
  }
  if (r < KTOP)
    srt[(size_t)img * KTOP + r] =
        make_float2(sj, __int_as_float((int)(((unsigned)gj) | ((unsigned)conf << 31))));
}

// ---- K3: compact conflicted list, exact greedy over it, scatter keeps ----
__global__ __launch_bounds__(1024)
void k_nms_scatter(const int* __restrict__ size_p,
                   const int* __restrict__ counts,
                   const float2* __restrict__ srt,
                   float* __restrict__ out) {
  const int img = blockIdx.x;
  const int tid = threadIdx.x;
  const int n = min(counts[img], CAP);
  const int m = min(n, KTOP);
  const float S = (float)size_p[0];
  const float A = 2.f * S * S;

  __shared__ float ssc[KTOP];
  __shared__ int   sgi[KTOP];
  __shared__ int   keepf[KTOP];
  __shared__ int   flag[KTOP];
  __shared__ int   scn[KTOP];
  __shared__ int   lst[KTOP];

  if (tid < m) {
    const float2 v = srt[(size_t)img * KTOP + tid];
    const unsigned w = (unsigned)__float_as_int(v.y);
    ssc[tid] = v.x;
    sgi[tid] = (int)(w & 0x7fffffffu);
    keepf[tid] = 1;
    flag[tid] = (int)(w >> 31);
  } else {
    keepf[tid] = 0;
    flag[tid] = 0;
  }
  __syncthreads();

  // inclusive Hillis-Steele scan of conflicted flags
  scn[tid] = flag[tid];
  __syncthreads();
  for (int off = 1; off < KTOP; off <<= 1) {
    int v = scn[tid];
    if (tid >= off) v += scn[tid - off];
    __syncthreads();
    scn[tid] = v;
    __syncthreads();
  }
  if (flag[tid]) lst[scn[tid] - 1] = tid;   // conflicted, in priority order
  const int nc = scn[KTOP - 1];
  __syncthreads();

  // exact greedy NMS restricted to the conflict graph (wave 0, serial outer,
  // 64-lane parallel inner). Isolated candidates can neither suppress nor be
  // suppressed, so this equals full greedy in top_k order.
  if (tid < 64) {
    for (int a = 1; a < nc; ++a) {
      const int j = lst[a];
      const int g = sgi[j];
      const int yj0 = g / NW;
      const float yjf = (float)yj0, xjf = (float)(g - yj0 * NW);
      bool sup = false;
      for (int base = 0; base < a; base += 64) {
        const int b = base + tid;
        bool hit = false;
        if (b < a) {
          const int i2 = lst[b];
          if (keepf[i2]) {
            const int g2 = sgi[i2];
            const int yi0 = g2 / NW;
            const float iy = S - fabsf(yjf - (float)yi0);
            const float ix = S - fabsf(xjf - (float)(g2 - yi0 * NW));
            hit = (fminf(iy, ix) > 0.f) && (11.f * iy * ix > A);
          }
        }
        if (__any(hit)) { sup = true; break; }
      }
      if (tid == 0 && sup) keepf[j] = 0;
    }
  }
  __syncthreads();

  if (tid < m && keepf[tid])
    out[(size_t)img * NHW + sgi[tid]] = ssc[tid];
}

// --------- fallback: monolithic per-image kernel (no workspace) ---------
__global__ __launch_bounds__(1024)
void k_nms_mono(const float* __restrict__ prob,
                const float* __restrict__ thr_p,
                const int* __restrict__ size_p,
                float* __restrict__ out) {
  const int img = blockIdx.x;
  const int tid = threadIdx.x;
  const float thr = thr_p[0];
  const float S = (float)size_p[0];
  const float A = 2.f * S * S;
  const float* ip = prob + (size_t)img * NHW;

  __shared__ float sc[CAP];
  __shared__ int   gi[CAP];
  __shared__ float ssc[KTOP];
  __shared__ int   sgi[KTOP];
  __shared__ int   keepf[KTOP];
  __shared__ int   sh_n;

  if (tid == 0) sh_n = 0;
  __syncthreads();
  for (int e = tid; e < NHW; e += 1024) {
    const float p = ip[e];
    if (p >= thr) {
      const int pos = atomicAdd(&sh_n, 1);
      if (pos < CAP) { sc[pos] = p; gi[pos] = e; }
    }
  }
  __syncthreads();
  const int n = min(sh_n, CAP);
  const int m = min(n, KTOP);

  for (int j = tid; j < n; j += 1024) {
    const float sj = sc[j]; const int gj = gi[j];
    int r = 0;
    for (int i = 0; i < n; ++i)
      r += (sc[i] > sj) || (sc[i] == sj && gi[i] < gj);
    if (r < KTOP) { ssc[r] = sj; sgi[r] = gj; }
  }
  keepf[tid] = (tid < m);
  __syncthreads();

  for (int i = 0; i < m; ++i) {
    __syncthreads();
    if (!keepf[i]) continue;
    const int g = sgi[i];
    const int yi0 = g / NW;
    const float yi = (float)yi0, xi = (float)(g - yi0 * NW);
    if (tid > i && tid < m && keepf[tid]) {
      const int g2 = sgi[tid];
      const int yj0 = g2 / NW;
      const float iy = S - fabsf(yi - (float)yj0);
      const float ix = S - fabsf(xi - (float)(g2 - yj0 * NW));
      if (fminf(iy, ix) > 0.f && 11.f * iy * ix > A) keepf[tid] = 0;
    }
  }
  __syncthreads();
  if (tid < m && keepf[tid])
    out[(size_t)img * NHW + sgi[tid]] = ssc[tid];
}

extern "C" void kernel_launch(void* const* d_in, const int* in_sizes, int n_in,
                              void* d_out, int out_size, void* d_ws, size_t ws_size,
                              hipStream_t stream) {
  const float* prob  = (const float*)d_in[0];
  const int*   size_p = (const int*)d_in[1];
  const float* thr_p  = (const float*)d_in[2];
  float* out = (float*)d_out;

  const size_t counts_b = NB * sizeof(int);
  const size_t cand_b   = (size_t)NB * CAP * sizeof(int);
  const size_t srt_b    = (size_t)NB * KTOP * sizeof(float2);
  const size_t needed   = counts_b + cand_b + srt_b;   // ~0.77 MB

  if (ws_size >= needed) {
    int*    counts = (int*)d_ws;
    int*    cand   = (int*)((char*)d_ws + counts_b);
    float2* srt    = (float2*)((char*)d_ws + counts_b + cand_b);
    k_zero_counts<<<1, 64, 0, stream>>>(counts);
    k_zero_gather<<<2048, 256, 0, stream>>>(prob, thr_p, out, counts, cand);
    dim3 g2(NB, CAP / 256);
    k_rank_conflict<<<g2, 256, 0, stream>>>(prob, size_p, counts, cand, srt);
    k_nms_scatter<<<NB, KTOP, 0, stream>>>(size_p, counts, srt, out);
  } else {
    k_zero_out<<<2048, 256, 0, stream>>>(out);
    k_nms_mono<<<NB, 1024, 0, stream>>>(prob, thr_p, size_p, out);
  }
}

// Round 2
// 125.088 us; speedup vs baseline: 2.7360x; 2.7360x over previous
//
#include <hip/hip_runtime.h>

#define NB 32
#define NH 720
#define NW 1280
#define NHW (NH * NW)        // 921600
#define NV4 (NHW / 4)        // 230400 float4 per image
#define KTOP 1024
#define CAP 2048             // gather capacity per image (~830 expected)
#define BPI 60               // blocks per image (NV4 % (BPI) aligned)
#define V4PB (NV4 / BPI)     // 3840 float4 per block
#define ITERS (V4PB / 256)   // 15
#define LCAP 512             // per-block candidate capacity (expected ~14)

// ------- K1: zero the output map + gather candidates >= threshold -------
// Each block owns a contiguous 3840-float4 chunk fully inside one image.
// Candidates stage in LDS; ONE global atomic per block reserves the slice.
__global__ __launch_bounds__(256)
void k_zero_gather(const float* __restrict__ prob,
                   const float* __restrict__ thr_p,
                   float* __restrict__ out,
                   int* __restrict__ counts,
                   float2* __restrict__ cand) {
  const int img = blockIdx.x / BPI;
  const int blk = blockIdx.x - img * BPI;
  const float thr = thr_p[0];

  __shared__ int lcount;
  __shared__ int lbase;
  __shared__ float2 lcand[LCAP];
  if (threadIdx.x == 0) lcount = 0;
  __syncthreads();

  const size_t base4 = (size_t)img * NV4 + (size_t)blk * V4PB;
  const float4 z = make_float4(0.f, 0.f, 0.f, 0.f);
#pragma unroll
  for (int it = 0; it < ITERS; ++it) {
    const size_t v = base4 + it * 256 + threadIdx.x;
    const float4 p = reinterpret_cast<const float4*>(prob)[v];
    reinterpret_cast<float4*>(out)[v] = z;
    const float vals[4] = {p.x, p.y, p.z, p.w};
    const int within4 = (int)(v - (size_t)img * NV4) * 4;
#pragma unroll
    for (int c = 0; c < 4; ++c) {
      if (vals[c] >= thr) {
        const int pos = atomicAdd(&lcount, 1);
        if (pos < LCAP)
          lcand[pos] = make_float2(vals[c], __int_as_float(within4 + c));
      }
    }
  }
  __syncthreads();

  const int ln = min(lcount, LCAP);
  if (threadIdx.x == 0) lbase = atomicAdd(&counts[img], ln);
  __syncthreads();
  const int b = lbase;
  for (int i = threadIdx.x; i < ln; i += 256) {
    const int pos = b + i;
    if (pos < CAP) cand[(size_t)img * CAP + pos] = lcand[i];
  }
}

// plain zeroing (fallback path)
__global__ void k_zero_out(float* __restrict__ out) {
  const int total4 = NB * NV4;
  const int stride = gridDim.x * blockDim.x;
  const float4 z = make_float4(0.f, 0.f, 0.f, 0.f);
  for (int v = blockIdx.x * blockDim.x + threadIdx.x; v < total4; v += stride)
    reinterpret_cast<float4*>(out)[v] = z;
}

// ---- K2: fused rank (stable top_k order) + conflict flag, per candidate ----
// grid = (NB, CAP/256), block = 256. Stage the image's candidate list in LDS;
// thread j does one O(n) pass computing:
//   rank = #{i : (s_i > s_j) or (s_i == s_j and idx_i < idx_j)}  (== top_k order)
//   conf = exists i != j with iou(i,j) > 0.1
// Writes (score, idx|conf<<31) to srt[rank] (rank < KTOP).
__global__ __launch_bounds__(256)
void k_rank_conflict(const int* __restrict__ size_p,
                     const int* __restrict__ counts,
                     const float2* __restrict__ cand,
                     float2* __restrict__ srt) {
  const int img = blockIdx.x;
  const int n = min(counts[img], CAP);
  const int j0 = blockIdx.y * 256;
  if (j0 >= n) return;
  const float S = (float)size_p[0];   // box side == 2*half (exact, even for odd size)
  const float A = 2.f * S * S;        // iou > 0.1  <=>  11*inter > A (exact small ints)

  __shared__ float4 cd[CAP];          // (score, y, x, idx-bits)
  for (int i = threadIdx.x; i < n; i += 256) {
    const float2 e2 = cand[(size_t)img * CAP + i];
    const int e = __float_as_int(e2.y);
    const int y = e / NW;
    cd[i] = make_float4(e2.x, (float)y, (float)(e - y * NW), e2.y);
  }
  __syncthreads();

  const int j = j0 + threadIdx.x;
  if (j >= n) return;
  const float4 me = cd[j];
  const float sj = me.x, yj = me.y, xj = me.z;
  const int gj = __float_as_int(me.w);
  int r = 0;
  int conf = 0;
  for (int i = 0; i < n; ++i) {
    const float4 o = cd[i];                       // same-address broadcast, no conflicts
    const int g2 = __float_as_int(o.w);
    r += (o.x > sj) || (o.x == sj && g2 < gj);    // stable top_k tie order
    const float iy = S - fabsf(yj - o.y);
    const float ix = S - fabsf(xj - o.z);
    const float inter = (fminf(iy, ix) > 0.f) ? iy * ix : 0.f;
    conf |= (int)((i != j) & (11.f * inter > A));
  }
  if (r < KTOP)
    srt[(size_t)img * KTOP + r] =
        make_float2(sj, __int_as_float((int)(((unsigned)gj) | ((unsigned)conf << 31))));
}

// ---- K3: compact conflicted list, exact greedy over it, scatter keeps ----
__global__ __launch_bounds__(1024)
void k_nms_scatter(const int* __restrict__ size_p,
                   const int* __restrict__ counts,
                   const float2* __restrict__ srt,
                   float* __restrict__ out) {
  const int img = blockIdx.x;
  const int tid = threadIdx.x;
  const int n = min(counts[img], CAP);
  const int m = min(n, KTOP);
  const float S = (float)size_p[0];
  const float A = 2.f * S * S;

  __shared__ float ssc[KTOP];
  __shared__ int   sgi[KTOP];
  __shared__ int   keepf[KTOP];
  __shared__ int   lst[KTOP];
  __shared__ int   wtot[16], wbase[16];
  __shared__ int   nc_sh;

  int flagv = 0;
  if (tid < m) {
    const float2 v = srt[(size_t)img * KTOP + tid];
    const unsigned w = (unsigned)__float_as_int(v.y);
    ssc[tid] = v.x;
    sgi[tid] = (int)(w & 0x7fffffffu);
    keepf[tid] = 1;
    flagv = (int)(w >> 31);
  } else {
    keepf[tid] = 0;
  }

  // ballot-based compaction of conflicted candidates (priority order preserved)
  const int wid = tid >> 6, lane = tid & 63;
  const unsigned long long mask = __ballot(flagv != 0);
  if (lane == 0) wtot[wid] = __popcll(mask);
  __syncthreads();
  if (tid == 0) {
    int s = 0;
    for (int w = 0; w < 16; ++w) { wbase[w] = s; s += wtot[w]; }
    nc_sh = s;
  }
  __syncthreads();
  if (flagv)
    lst[wbase[wid] + __popcll(mask & ((1ull << lane) - 1ull))] = tid;
  const int nc = nc_sh;
  __syncthreads();

  // exact greedy NMS restricted to the conflict graph (wave 0 only).
  // Isolated candidates can neither suppress nor be suppressed, so this
  // equals full greedy over top_k order.
  if (tid < 64) {
    for (int a = 1; a < nc; ++a) {
      const int j = lst[a];
      const int g = sgi[j];
      const int yj0 = g / NW;
      const float yjf = (float)yj0, xjf = (float)(g - yj0 * NW);
      bool sup = false;
      for (int base = 0; base < a; base += 64) {
        const int b = base + tid;
        bool hit = false;
        if (b < a) {
          const int i2 = lst[b];
          if (keepf[i2]) {
            const int g2 = sgi[i2];
            const int yi0 = g2 / NW;
            const float iy = S - fabsf(yjf - (float)yi0);
            const float ix = S - fabsf(xjf - (float)(g2 - yi0 * NW));
            hit = (fminf(iy, ix) > 0.f) && (11.f * iy * ix > A);
          }
        }
        if (__any(hit)) { sup = true; break; }
      }
      if (tid == 0 && sup) keepf[j] = 0;
    }
  }
  __syncthreads();

  if (tid < m && keepf[tid])
    out[(size_t)img * NHW + sgi[tid]] = ssc[tid];
}

// --------- fallback: monolithic per-image kernel (no workspace) ---------
__global__ __launch_bounds__(1024)
void k_nms_mono(const float* __restrict__ prob,
                const float* __restrict__ thr_p,
                const int* __restrict__ size_p,
                float* __restrict__ out) {
  const int img = blockIdx.x;
  const int tid = threadIdx.x;
  const float thr = thr_p[0];
  const float S = (float)size_p[0];
  const float A = 2.f * S * S;
  const float* ip = prob + (size_t)img * NHW;

  __shared__ float sc[CAP];
  __shared__ int   gi[CAP];
  __shared__ float ssc[KTOP];
  __shared__ int   sgi[KTOP];
  __shared__ int   keepf[KTOP];
  __shared__ int   sh_n;

  if (tid == 0) sh_n = 0;
  __syncthreads();
  for (int e = tid; e < NHW; e += 1024) {
    const float p = ip[e];
    if (p >= thr) {
      const int pos = atomicAdd(&sh_n, 1);
      if (pos < CAP) { sc[pos] = p; gi[pos] = e; }
    }
  }
  __syncthreads();
  const int n = min(sh_n, CAP);
  const int m = min(n, KTOP);

  for (int j = tid; j < n; j += 1024) {
    const float sj = sc[j]; const int gj = gi[j];
    int r = 0;
    for (int i = 0; i < n; ++i)
      r += (sc[i] > sj) || (sc[i] == sj && gi[i] < gj);
    if (r < KTOP) { ssc[r] = sj; sgi[r] = gj; }
  }
  keepf[tid] = (tid < m);
  __syncthreads();

  for (int i = 0; i < m; ++i) {
    __syncthreads();
    if (!keepf[i]) continue;
    const int g = sgi[i];
    const int yi0 = g / NW;
    const float yi = (float)yi0, xi = (float)(g - yi0 * NW);
    if (tid > i && tid < m && keepf[tid]) {
      const int g2 = sgi[tid];
      const int yj0 = g2 / NW;
      const float iy = S - fabsf(yi - (float)yj0);
      const float ix = S - fabsf(xi - (float)(g2 - yj0 * NW));
      if (fminf(iy, ix) > 0.f && 11.f * iy * ix > A) keepf[tid] = 0;
    }
  }
  __syncthreads();
  if (tid < m && keepf[tid])
    out[(size_t)img * NHW + sgi[tid]] = ssc[tid];
}

extern "C" void kernel_launch(void* const* d_in, const int* in_sizes, int n_in,
                              void* d_out, int out_size, void* d_ws, size_t ws_size,
                              hipStream_t stream) {
  const float* prob   = (const float*)d_in[0];
  const int*   size_p = (const int*)d_in[1];
  const float* thr_p  = (const float*)d_in[2];
  float* out = (float*)d_out;

  const size_t counts_b = 128;                              // NB ints, padded
  const size_t cand_b   = (size_t)NB * CAP * sizeof(float2);
  const size_t srt_b    = (size_t)NB * KTOP * sizeof(float2);
  const size_t needed   = counts_b + cand_b + srt_b;        // ~0.79 MB

  if (ws_size >= needed) {
    int*    counts = (int*)d_ws;
    float2* cand   = (float2*)((char*)d_ws + counts_b);
    float2* srt    = (float2*)((char*)d_ws + counts_b + cand_b);
    hipMemsetAsync(counts, 0, NB * sizeof(int), stream);
    k_zero_gather<<<NB * BPI, 256, 0, stream>>>(prob, thr_p, out, counts, cand);
    dim3 g2(NB, CAP / 256);
    k_rank_conflict<<<g2, 256, 0, stream>>>(size_p, counts, cand, srt);
    k_nms_scatter<<<NB, KTOP, 0, stream>>>(size_p, counts, srt, out);
  } else {
    k_zero_out<<<2048, 256, 0, stream>>>(out);
    k_nms_mono<<<NB, 1024, 0, stream>>>(prob, thr_p, size_p, out);
  }
}